// Round 1
// baseline (1316.551 us; speedup 1.0000x reference)
//
#include <hip/hip_runtime.h>

#define NB    2048
#define AMAX  64
#define EDIM  128
#define NH    8
#define DHEAD 16
#define XSTR  129   // xs row stride: (129*L + k) % 32 = (L+k)%32 -> 2-way, free
#define KVSTR 20    // 80B rows: 16B-aligned for b128 broadcast reads

// ---------------- offsets: exclusive prefix sum of agents_per_sample ----------------
__global__ __launch_bounds__(256) void scan_kernel(const int* __restrict__ ag,
                                                   int* __restrict__ offs) {
    __shared__ int part[256];
    const int t = threadIdx.x;
    int loc[8];
    int s = 0;
#pragma unroll
    for (int i = 0; i < 8; ++i) { loc[i] = s; s += ag[t * 8 + i]; }
    part[t] = s;
    __syncthreads();
    for (int d = 1; d < 256; d <<= 1) {
        int v = (t >= d) ? part[t - d] : 0;
        __syncthreads();
        part[t] += v;
        __syncthreads();
    }
    const int base = (t == 0) ? 0 : part[t - 1];
#pragma unroll
    for (int i = 0; i < 8; ++i) offs[t * 8 + i] = base + loc[i];
}

// ---------------- fused ragged MHSA: one block per sample ----------------
__global__ __launch_bounds__(256, 2) void attn_kernel(
    const float* __restrict__ x,     // [total,128]
    const float* __restrict__ win,   // [384,128]
    const float* __restrict__ bin,   // [384]
    const float* __restrict__ wout,  // [128,128]
    const float* __restrict__ bout,  // [128]
    const int*   __restrict__ ag,
    const int*   __restrict__ offs,
    float* __restrict__ out)         // [total,128]
{
    __shared__ __align__(16) float xs[AMAX * XSTR];        // X, later reused for ctx
    __shared__ __align__(16) float kvs[8][AMAX * KVSTR];   // per-wave {k,v}

    const int b    = blockIdx.x;
    const int n    = ag[b];
    const int off  = offs[b];
    const int tid  = threadIdx.x;
    const int lane = tid & 63;
    // wave id as provable SGPR -> all weight/bias loads scalarize (s_load)
    const int wid  = __builtin_amdgcn_readfirstlane(tid >> 6);

    // ---- phase 0: stage X, zero rows >= n (avoids NaN/garbage downstream) ----
#pragma unroll
    for (int it = 0; it < 8; ++it) {
        const int f4 = it * 256 + tid;       // 2048 float4 = 64 rows * 32
        const int r  = f4 >> 5;
        const int c  = (f4 & 31) << 2;
        float4 v = make_float4(0.f, 0.f, 0.f, 0.f);
        if (r < n) v = *(const float4*)(x + (size_t)(off + r) * EDIM + c);
        float* d = xs + r * XSTR + c;
        d[0] = v.x; d[1] = v.y; d[2] = v.z; d[3] = v.w;
    }
    __syncthreads();

    float* kw = kvs[wid * 2 + 0];
    float* vw = kvs[wid * 2 + 1];
    const float* xrow = xs + lane * XSTR;

    float ctxk[2][DHEAD];                    // ctx for this wave's 2 heads

#pragma unroll
    for (int m = 0; m < 2; ++m) {
        const int h = wid * 2 + m;

        // ---- phase 1: q,k,v rows (lane = agent row), scalar W streams ----
        float qa[DHEAD], ka[DHEAD], va[DHEAD];
#pragma unroll
        for (int d = 0; d < DHEAD; ++d) { qa[d] = 0.f; ka[d] = 0.f; va[d] = 0.f; }
        const float* wq = win + (size_t)(h * DHEAD) * EDIM;
        const float* wk = win + (size_t)(EDIM + h * DHEAD) * EDIM;
        const float* wv = win + (size_t)(2 * EDIM + h * DHEAD) * EDIM;
        for (int k = 0; k < EDIM; ++k) {
            const float xv = xrow[k];
#pragma unroll
            for (int d = 0; d < DHEAD; ++d) {
                qa[d] = fmaf(xv, wq[d * EDIM + k], qa[d]);
                ka[d] = fmaf(xv, wk[d * EDIM + k], ka[d]);
                va[d] = fmaf(xv, wv[d * EDIM + k], va[d]);
            }
        }
#pragma unroll
        for (int d = 0; d < DHEAD; ++d) {
            qa[d] = (qa[d] + bin[h * DHEAD + d]) * 0.25f;   // fold 1/sqrt(16) into q
            ka[d] += bin[EDIM + h * DHEAD + d];
            va[d] += bin[2 * EDIM + h * DHEAD + d];
        }
        // stash k,v rows in wave-private LDS (wave-synchronous, no barrier needed)
#pragma unroll
        for (int d = 0; d < DHEAD; ++d) {
            kw[lane * KVSTR + d] = ka[d];
            vw[lane * KVSTR + d] = va[d];
        }

        // ---- phases 2-4: online softmax over key chunks of 16 ----
        float mrun = -1e30f, lrun = 0.f;
        float cacc[DHEAD];
#pragma unroll
        for (int d = 0; d < DHEAD; ++d) cacc[d] = 0.f;
        const int nch = (n + 15) >> 4;
        for (int ch = 0; ch < nch; ++ch) {
            const int jb = ch << 4;
            float s[16], p[16];
#pragma unroll
            for (int jj = 0; jj < 16; ++jj) {
                const float4* kr = (const float4*)(kw + (jb + jj) * KVSTR);
                const float4 k0 = kr[0], k1 = kr[1], k2 = kr[2], k3 = kr[3];
                const float kk[16] = {k0.x,k0.y,k0.z,k0.w, k1.x,k1.y,k1.z,k1.w,
                                      k2.x,k2.y,k2.z,k2.w, k3.x,k3.y,k3.z,k3.w};
                float acc = 0.f;
#pragma unroll
                for (int d = 0; d < DHEAD; ++d) acc = fmaf(qa[d], kk[d], acc);
                s[jj] = (jb + jj < n) ? acc : -1e30f;
            }
            float mc = s[0];
#pragma unroll
            for (int jj = 1; jj < 16; ++jj) mc = fmaxf(mc, s[jj]);
            const float mnew  = fmaxf(mrun, mc);
            const float alpha = __expf(mrun - mnew);
            float psum = 0.f;
#pragma unroll
            for (int jj = 0; jj < 16; ++jj) { p[jj] = __expf(s[jj] - mnew); psum += p[jj]; }
            lrun = fmaf(lrun, alpha, psum);
#pragma unroll
            for (int d = 0; d < DHEAD; ++d) cacc[d] *= alpha;
#pragma unroll
            for (int jj = 0; jj < 16; ++jj) {
                const float4* vr = (const float4*)(vw + (jb + jj) * KVSTR);
                const float4 v0 = vr[0], v1 = vr[1], v2 = vr[2], v3 = vr[3];
                const float vv[16] = {v0.x,v0.y,v0.z,v0.w, v1.x,v1.y,v1.z,v1.w,
                                      v2.x,v2.y,v2.z,v2.w, v3.x,v3.y,v3.z,v3.w};
                const float pj = p[jj];
#pragma unroll
                for (int d = 0; d < DHEAD; ++d) cacc[d] = fmaf(pj, vv[d], cacc[d]);
            }
            mrun = mnew;
        }
        const float inv = 1.0f / lrun;
#pragma unroll
        for (int d = 0; d < DHEAD; ++d) ctxk[m][d] = cacc[d] * inv;
    }

    __syncthreads();   // all waves done reading xs -> safe to reuse as ctx
#pragma unroll
    for (int m = 0; m < 2; ++m) {
        const int h = wid * 2 + m;
#pragma unroll
        for (int d = 0; d < DHEAD; ++d)
            xs[lane * XSTR + h * DHEAD + d] = ctxk[m][d];
    }
    __syncthreads();

    // ---- phase 5: out = ctx @ wout^T + bout; wave w owns 32 cols ----
    const int c0 = wid * 32;
#pragma unroll
    for (int ct = 0; ct < 4; ++ct) {
        const int cc = c0 + ct * 8;
        float a8[8];
#pragma unroll
        for (int j = 0; j < 8; ++j) a8[j] = 0.f;
#pragma unroll 4
        for (int e = 0; e < EDIM; ++e) {
            const float cv = xrow[e];
#pragma unroll
            for (int j = 0; j < 8; ++j)
                a8[j] = fmaf(cv, wout[(size_t)(cc + j) * EDIM + e], a8[j]);
        }
        if (lane < n) {
            float* orow = out + (size_t)(off + lane) * EDIM + cc;
#pragma unroll
            for (int j = 0; j < 8; ++j) orow[j] = a8[j] + bout[cc + j];
        }
    }
}

extern "C" void kernel_launch(void* const* d_in, const int* in_sizes, int n_in,
                              void* d_out, int out_size, void* d_ws, size_t ws_size,
                              hipStream_t stream) {
    const float* x   = (const float*)d_in[0];
    const float* win = (const float*)d_in[1];
    const float* bin = (const float*)d_in[2];
    const float* wo  = (const float*)d_in[3];
    const float* bo  = (const float*)d_in[4];
    const int*   ag  = (const int*)d_in[5];
    float* out = (float*)d_out;
    int*   offs = (int*)d_ws;   // 2048 ints

    scan_kernel<<<1, 256, 0, stream>>>(ag, offs);
    attn_kernel<<<NB, 256, 0, stream>>>(x, win, bin, wo, bo, ag, offs, out);
}

// Round 2
// 310.010 us; speedup vs baseline: 4.2468x; 4.2468x over previous
//
#include <hip/hip_runtime.h>

#define NB    2048
#define AMAX  64
#define EDIM  128
#define TOTAL 66560          // = 520 * 128, exact
#define DHEAD 16
#define KVSTR 20             // 80B rows: 16B-aligned b128 broadcast reads
#define XSTR  129            // fallback kernel xs stride

// ---- ws layout (floats) for the split path ----
#define QKV_OFF  0
#define CTX_OFF  ((size_t)TOTAL * 384)
#define OFFS_OFF (CTX_OFF + (size_t)TOTAL * 128)
#define WS_NEEDED ((OFFS_OFF + NB) * 4)

// ---------------- offsets: exclusive prefix sum ----------------
__global__ __launch_bounds__(256) void scan_kernel(const int* __restrict__ ag,
                                                   int* __restrict__ offs) {
    __shared__ int part[256];
    const int t = threadIdx.x;
    int loc[8];
    int s = 0;
#pragma unroll
    for (int i = 0; i < 8; ++i) { loc[i] = s; s += ag[t * 8 + i]; }
    part[t] = s;
    __syncthreads();
    for (int d = 1; d < 256; d <<= 1) {
        int v = (t >= d) ? part[t - d] : 0;
        __syncthreads();
        part[t] += v;
        __syncthreads();
    }
    const int base = (t == 0) ? 0 : part[t - 1];
#pragma unroll
    for (int i = 0; i < 8; ++i) offs[t * 8 + i] = base + loc[i];
}

// ---------------- tiled GEMM: C[M x N] = A[M x 128] @ B[N x 128]^T + bias ----------------
// M multiple of 128, N multiple of 128. grid = (M/128, N/128), 256 threads.
// micro-tile strided by 16 so LDS b128 reads are broadcast (A) / 2-way (B) = conflict-free.
__global__ __launch_bounds__(256, 2) void gemm_kernel(
    const float* __restrict__ Am, const float* __restrict__ Bm,
    const float* __restrict__ bias, float* __restrict__ Cm, int N)
{
    __shared__ __align__(16) float As[128 * 68];
    __shared__ __align__(16) float Bs[128 * 68];
    const int tid = threadIdx.x;
    const int tx = tid & 15;          // col group: cols tx + 16j
    const int ty = tid >> 4;          // row group: rows ty + 16i
    const int rowbase = blockIdx.x * 128;
    const int colbase = blockIdx.y * 128;

    float acc[8][8];
#pragma unroll
    for (int i = 0; i < 8; ++i)
#pragma unroll
        for (int j = 0; j < 8; ++j) acc[i][j] = 0.f;

#pragma unroll
    for (int ks = 0; ks < 2; ++ks) {
        const int kb = ks * 64;
        // ---- stage A half-tile and B half-tile (coalesced float4) ----
#pragma unroll
        for (int it = 0; it < 8; ++it) {
            const int idx = it * 256 + tid;          // 2048 f4 = 128 rows x 16 f4
            const int r  = idx >> 4;
            const int c4 = (idx & 15) << 2;
            const float4 av = *(const float4*)(Am + (size_t)(rowbase + r) * EDIM + kb + c4);
            const float4 bv = *(const float4*)(Bm + (size_t)(colbase + r) * EDIM + kb + c4);
            *(float4*)(As + r * 68 + c4) = av;
            *(float4*)(Bs + r * 68 + c4) = bv;
        }
        __syncthreads();
        // ---- 16 k4-steps over this 64-wide k slab ----
#pragma unroll 2
        for (int k4 = 0; k4 < 16; ++k4) {
            float4 a4[8], b4[8];
#pragma unroll
            for (int i = 0; i < 8; ++i)
                a4[i] = *(const float4*)(As + (ty + 16 * i) * 68 + k4 * 4);
#pragma unroll
            for (int j = 0; j < 8; ++j)
                b4[j] = *(const float4*)(Bs + (tx + 16 * j) * 68 + k4 * 4);
#pragma unroll
            for (int i = 0; i < 8; ++i)
#pragma unroll
                for (int j = 0; j < 8; ++j) {
                    acc[i][j] = fmaf(a4[i].x, b4[j].x, acc[i][j]);
                    acc[i][j] = fmaf(a4[i].y, b4[j].y, acc[i][j]);
                    acc[i][j] = fmaf(a4[i].z, b4[j].z, acc[i][j]);
                    acc[i][j] = fmaf(a4[i].w, b4[j].w, acc[i][j]);
                }
        }
        __syncthreads();
    }

    // ---- epilogue: + bias, scalar stores (coalesced across lanes) ----
    float bj[8];
#pragma unroll
    for (int j = 0; j < 8; ++j) bj[j] = bias[colbase + tx + 16 * j];
#pragma unroll
    for (int i = 0; i < 8; ++i) {
        const size_t row = rowbase + ty + 16 * i;
#pragma unroll
        for (int j = 0; j < 8; ++j)
            Cm[row * N + colbase + tx + 16 * j] = acc[i][j] + bj[j];
    }
}

// ---------------- per-sample flash attention over precomputed QKV ----------------
__global__ __launch_bounds__(256, 4) void attn2_kernel(
    const float* __restrict__ qkv,   // [TOTAL][384] = q|k|v
    const int*   __restrict__ ag,
    const int*   __restrict__ offs,
    float* __restrict__ ctx)         // [TOTAL][128]
{
    __shared__ __align__(16) float kvs[8][AMAX * KVSTR];
    const int b    = blockIdx.x;
    const int n    = ag[b];
    const int off  = offs[b];
    const int tid  = threadIdx.x;
    const int lane = tid & 63;
    const int wid  = __builtin_amdgcn_readfirstlane(tid >> 6);
    float* kw = kvs[wid * 2 + 0];
    float* vw = kvs[wid * 2 + 1];
    const bool valid = lane < n;
    const float* rowp = qkv + (size_t)(off + lane) * 384;

#pragma unroll
    for (int m = 0; m < 2; ++m) {
        const int h = wid * 2 + m;
        float qa[DHEAD], ka[DHEAD], va[DHEAD];
        if (valid) {
#pragma unroll
            for (int d4 = 0; d4 < 4; ++d4) {
                const float4 qv = *(const float4*)(rowp + h * DHEAD + d4 * 4);
                const float4 kv = *(const float4*)(rowp + 128 + h * DHEAD + d4 * 4);
                const float4 vv = *(const float4*)(rowp + 256 + h * DHEAD + d4 * 4);
                qa[d4*4+0]=qv.x; qa[d4*4+1]=qv.y; qa[d4*4+2]=qv.z; qa[d4*4+3]=qv.w;
                ka[d4*4+0]=kv.x; ka[d4*4+1]=kv.y; ka[d4*4+2]=kv.z; ka[d4*4+3]=kv.w;
                va[d4*4+0]=vv.x; va[d4*4+1]=vv.y; va[d4*4+2]=vv.z; va[d4*4+3]=vv.w;
            }
        } else {
#pragma unroll
            for (int d = 0; d < DHEAD; ++d) { qa[d]=0.f; ka[d]=0.f; va[d]=0.f; }
        }
#pragma unroll
        for (int d = 0; d < DHEAD; ++d) qa[d] *= 0.25f;   // 1/sqrt(16)
        // every lane writes its row (zeros for pad rows) -> no uninitialized LDS
#pragma unroll
        for (int d4 = 0; d4 < 4; ++d4) {
            *(float4*)(kw + lane * KVSTR + d4 * 4) = make_float4(ka[d4*4], ka[d4*4+1], ka[d4*4+2], ka[d4*4+3]);
            *(float4*)(vw + lane * KVSTR + d4 * 4) = make_float4(va[d4*4], va[d4*4+1], va[d4*4+2], va[d4*4+3]);
        }

        float mrun = -1e30f, lrun = 0.f;
        float cacc[DHEAD];
#pragma unroll
        for (int d = 0; d < DHEAD; ++d) cacc[d] = 0.f;
        const int nch = (n + 15) >> 4;
        for (int ch = 0; ch < nch; ++ch) {
            const int jb = ch << 4;
            float s[16], p[16];
#pragma unroll
            for (int jj = 0; jj < 16; ++jj) {
                const float4* kr = (const float4*)(kw + (jb + jj) * KVSTR);
                const float4 k0 = kr[0], k1 = kr[1], k2 = kr[2], k3 = kr[3];
                const float kk[16] = {k0.x,k0.y,k0.z,k0.w, k1.x,k1.y,k1.z,k1.w,
                                      k2.x,k2.y,k2.z,k2.w, k3.x,k3.y,k3.z,k3.w};
                float a = 0.f;
#pragma unroll
                for (int d = 0; d < DHEAD; ++d) a = fmaf(qa[d], kk[d], a);
                s[jj] = (jb + jj < n) ? a : -1e30f;
            }
            float mc = s[0];
#pragma unroll
            for (int jj = 1; jj < 16; ++jj) mc = fmaxf(mc, s[jj]);
            const float mnew  = fmaxf(mrun, mc);
            const float alpha = __expf(mrun - mnew);
            float psum = 0.f;
#pragma unroll
            for (int jj = 0; jj < 16; ++jj) { p[jj] = __expf(s[jj] - mnew); psum += p[jj]; }
            lrun = fmaf(lrun, alpha, psum);
#pragma unroll
            for (int d = 0; d < DHEAD; ++d) cacc[d] *= alpha;
#pragma unroll
            for (int jj = 0; jj < 16; ++jj) {
                const float4* vr = (const float4*)(vw + (jb + jj) * KVSTR);
                const float4 v0 = vr[0], v1 = vr[1], v2 = vr[2], v3 = vr[3];
                const float vv[16] = {v0.x,v0.y,v0.z,v0.w, v1.x,v1.y,v1.z,v1.w,
                                      v2.x,v2.y,v2.z,v2.w, v3.x,v3.y,v3.z,v3.w};
                const float pj = p[jj];
#pragma unroll
                for (int d = 0; d < DHEAD; ++d) cacc[d] = fmaf(pj, vv[d], cacc[d]);
            }
            mrun = mnew;
        }
        if (valid) {
            const float inv = 1.0f / lrun;
            float* crow = ctx + (size_t)(off + lane) * 128 + h * DHEAD;
#pragma unroll
            for (int d4 = 0; d4 < 4; ++d4)
                *(float4*)(crow + d4 * 4) = make_float4(cacc[d4*4]*inv, cacc[d4*4+1]*inv,
                                                        cacc[d4*4+2]*inv, cacc[d4*4+3]*inv);
        }
    }
}

// ================= fallback: round-1 fused kernel (used if ws too small) =================
__global__ __launch_bounds__(256, 2) void attn_fused_kernel(
    const float* __restrict__ x, const float* __restrict__ win,
    const float* __restrict__ bin, const float* __restrict__ wout,
    const float* __restrict__ bout, const int* __restrict__ ag,
    const int* __restrict__ offs, float* __restrict__ out)
{
    __shared__ __align__(16) float xs[AMAX * XSTR];
    __shared__ __align__(16) float kvs[8][AMAX * KVSTR];
    const int b = blockIdx.x, n = ag[b], off = offs[b];
    const int tid = threadIdx.x, lane = tid & 63;
    const int wid = __builtin_amdgcn_readfirstlane(tid >> 6);
#pragma unroll
    for (int it = 0; it < 8; ++it) {
        const int f4 = it * 256 + tid;
        const int r = f4 >> 5, c = (f4 & 31) << 2;
        float4 v = make_float4(0.f, 0.f, 0.f, 0.f);
        if (r < n) v = *(const float4*)(x + (size_t)(off + r) * EDIM + c);
        float* d = xs + r * XSTR + c;
        d[0]=v.x; d[1]=v.y; d[2]=v.z; d[3]=v.w;
    }
    __syncthreads();
    float* kw = kvs[wid*2+0]; float* vw = kvs[wid*2+1];
    const float* xrow = xs + lane * XSTR;
    float ctxk[2][DHEAD];
#pragma unroll
    for (int m = 0; m < 2; ++m) {
        const int h = wid * 2 + m;
        float qa[DHEAD], ka[DHEAD], va[DHEAD];
#pragma unroll
        for (int d = 0; d < DHEAD; ++d) { qa[d]=0.f; ka[d]=0.f; va[d]=0.f; }
        const float* wq = win + (size_t)(h*DHEAD)*EDIM;
        const float* wk = win + (size_t)(EDIM + h*DHEAD)*EDIM;
        const float* wv = win + (size_t)(2*EDIM + h*DHEAD)*EDIM;
        for (int k = 0; k < EDIM; ++k) {
            const float xv = xrow[k];
#pragma unroll
            for (int d = 0; d < DHEAD; ++d) {
                qa[d] = fmaf(xv, wq[d*EDIM+k], qa[d]);
                ka[d] = fmaf(xv, wk[d*EDIM+k], ka[d]);
                va[d] = fmaf(xv, wv[d*EDIM+k], va[d]);
            }
        }
#pragma unroll
        for (int d = 0; d < DHEAD; ++d) {
            qa[d] = (qa[d] + bin[h*DHEAD+d]) * 0.25f;
            ka[d] += bin[EDIM + h*DHEAD + d];
            va[d] += bin[2*EDIM + h*DHEAD + d];
        }
#pragma unroll
        for (int d = 0; d < DHEAD; ++d) { kw[lane*KVSTR+d] = ka[d]; vw[lane*KVSTR+d] = va[d]; }
        float mrun = -1e30f, lrun = 0.f, cacc[DHEAD];
#pragma unroll
        for (int d = 0; d < DHEAD; ++d) cacc[d] = 0.f;
        const int nch = (n + 15) >> 4;
        for (int ch = 0; ch < nch; ++ch) {
            const int jb = ch << 4;
            float s[16], p[16];
#pragma unroll
            for (int jj = 0; jj < 16; ++jj) {
                const float4* kr = (const float4*)(kw + (jb + jj) * KVSTR);
                const float4 k0=kr[0],k1=kr[1],k2=kr[2],k3=kr[3];
                const float kk[16] = {k0.x,k0.y,k0.z,k0.w,k1.x,k1.y,k1.z,k1.w,
                                      k2.x,k2.y,k2.z,k2.w,k3.x,k3.y,k3.z,k3.w};
                float a = 0.f;
#pragma unroll
                for (int d = 0; d < DHEAD; ++d) a = fmaf(qa[d], kk[d], a);
                s[jj] = (jb + jj < n) ? a : -1e30f;
            }
            float mc = s[0];
#pragma unroll
            for (int jj = 1; jj < 16; ++jj) mc = fmaxf(mc, s[jj]);
            const float mnew = fmaxf(mrun, mc);
            const float alpha = __expf(mrun - mnew);
            float psum = 0.f;
#pragma unroll
            for (int jj = 0; jj < 16; ++jj) { p[jj] = __expf(s[jj]-mnew); psum += p[jj]; }
            lrun = fmaf(lrun, alpha, psum);
#pragma unroll
            for (int d = 0; d < DHEAD; ++d) cacc[d] *= alpha;
#pragma unroll
            for (int jj = 0; jj < 16; ++jj) {
                const float4* vr = (const float4*)(vw + (jb + jj) * KVSTR);
                const float4 v0=vr[0],v1=vr[1],v2=vr[2],v3=vr[3];
                const float vv[16] = {v0.x,v0.y,v0.z,v0.w,v1.x,v1.y,v1.z,v1.w,
                                      v2.x,v2.y,v2.z,v2.w,v3.x,v3.y,v3.z,v3.w};
                const float pj = p[jj];
#pragma unroll
                for (int d = 0; d < DHEAD; ++d) cacc[d] = fmaf(pj, vv[d], cacc[d]);
            }
            mrun = mnew;
        }
        const float inv = 1.0f / lrun;
#pragma unroll
        for (int d = 0; d < DHEAD; ++d) ctxk[m][d] = cacc[d] * inv;
    }
    __syncthreads();
#pragma unroll
    for (int m = 0; m < 2; ++m) {
        const int h = wid * 2 + m;
#pragma unroll
        for (int d = 0; d < DHEAD; ++d) xs[lane*XSTR + h*DHEAD + d] = ctxk[m][d];
    }
    __syncthreads();
    const int c0 = wid * 32;
#pragma unroll
    for (int ct = 0; ct < 4; ++ct) {
        const int cc = c0 + ct * 8;
        float a8[8];
#pragma unroll
        for (int j = 0; j < 8; ++j) a8[j] = 0.f;
#pragma unroll 4
        for (int e = 0; e < EDIM; ++e) {
            const float cv = xrow[e];
#pragma unroll
            for (int j = 0; j < 8; ++j) a8[j] = fmaf(cv, wout[(size_t)(cc+j)*EDIM+e], a8[j]);
        }
        if (lane < n) {
            float* orow = out + (size_t)(off + lane) * EDIM + cc;
#pragma unroll
            for (int j = 0; j < 8; ++j) orow[j] = a8[j] + bout[cc+j];
        }
    }
}

extern "C" void kernel_launch(void* const* d_in, const int* in_sizes, int n_in,
                              void* d_out, int out_size, void* d_ws, size_t ws_size,
                              hipStream_t stream) {
    const float* x   = (const float*)d_in[0];
    const float* win = (const float*)d_in[1];
    const float* bin = (const float*)d_in[2];
    const float* wo  = (const float*)d_in[3];
    const float* bo  = (const float*)d_in[4];
    const int*   ag  = (const int*)d_in[5];
    float* out = (float*)d_out;

    if (ws_size >= WS_NEEDED) {
        float* qkv = (float*)d_ws + QKV_OFF;
        float* ctx = (float*)d_ws + CTX_OFF;
        int*   offs = (int*)((float*)d_ws + OFFS_OFF);
        scan_kernel<<<1, 256, 0, stream>>>(ag, offs);
        gemm_kernel<<<dim3(TOTAL / 128, 3), 256, 0, stream>>>(x, win, bin, qkv, 384);
        attn2_kernel<<<NB, 256, 0, stream>>>(qkv, ag, offs, ctx);
        gemm_kernel<<<dim3(TOTAL / 128, 1), 256, 0, stream>>>(ctx, wo, bo, out, 128);
    } else {
        int* offs = (int*)d_ws;
        scan_kernel<<<1, 256, 0, stream>>>(ag, offs);
        attn_fused_kernel<<<NB, 256, 0, stream>>>(x, win, bin, wo, bo, ag, offs, out);
    }
}

// Round 5
// 200.520 us; speedup vs baseline: 6.5657x; 1.5460x over previous
//
#include <hip/hip_runtime.h>

#define NB    2048
#define AMAX  64
#define EDIM  128
#define TOTAL 66560          // = 520 * 128
#define DHEAD 16
#define KVSTR 20
#define XSTR  129
#define LSTR  136            // LDS row stride in fp16 (128 + 8 pad)

typedef _Float16 f16x8 __attribute__((ext_vector_type(8)));
typedef _Float16 f16x4 __attribute__((ext_vector_type(4)));
typedef float    f32x4 __attribute__((ext_vector_type(4)));

// ---------------- offsets: exclusive prefix sum ----------------
__global__ __launch_bounds__(256) void scan_kernel(const int* __restrict__ ag,
                                                   int* __restrict__ offs) {
    __shared__ int part[256];
    const int t = threadIdx.x;
    int loc[8];
    int s = 0;
#pragma unroll
    for (int i = 0; i < 8; ++i) { loc[i] = s; s += ag[t * 8 + i]; }
    part[t] = s;
    __syncthreads();
    for (int d = 1; d < 256; d <<= 1) {
        int v = (t >= d) ? part[t - d] : 0;
        __syncthreads();
        part[t] += v;
        __syncthreads();
    }
    const int base = (t == 0) ? 0 : part[t - 1];
#pragma unroll
    for (int i = 0; i < 8; ++i) offs[t * 8 + i] = base + loc[i];
}

// ---------------- QKV GEMM: qkv_h[M x 384] = x_f32[M x 128] @ win^T + bin ----------------
// tile 128x128, K=128 one LDS stage. grid = (3, M/128), 256 thr.
// Swapped-operand mfma: lane holds row = l15 (+16r +32wid), cols = c*16 + quad*4 + [0..3].
__global__ __launch_bounds__(256, 2) void gemm_qkv_kernel(
    const float* __restrict__ Ain,   // f32 [M][128]
    const float* __restrict__ Bin,   // f32 [384][128]
    const float* __restrict__ bias,  // f32 [384]
    _Float16*    __restrict__ Cout)  // f16 [M][384]
{
    __shared__ __align__(16) _Float16 As[128 * LSTR];
    __shared__ __align__(16) _Float16 Bs[128 * LSTR];
    const int tid = threadIdx.x;
    const int rowbase = blockIdx.y * 128;
    const int colbase = blockIdx.x * 128;

    {
        const float* A = Ain + (size_t)rowbase * EDIM;
        const float* B = Bin + (size_t)colbase * EDIM;
#pragma unroll
        for (int it = 0; it < 8; ++it) {
            const int u = it * 256 + tid;            // 2048 units of 8 halfs
            const int r = u >> 4, c8 = u & 15;
            const float4 a0 = *(const float4*)(A + r * EDIM + c8 * 8);
            const float4 a1 = *(const float4*)(A + r * EDIM + c8 * 8 + 4);
            const float4 b0 = *(const float4*)(B + r * EDIM + c8 * 8);
            const float4 b1 = *(const float4*)(B + r * EDIM + c8 * 8 + 4);
            f16x8 ha, hb;
            ha[0]=(_Float16)a0.x; ha[1]=(_Float16)a0.y; ha[2]=(_Float16)a0.z; ha[3]=(_Float16)a0.w;
            ha[4]=(_Float16)a1.x; ha[5]=(_Float16)a1.y; ha[6]=(_Float16)a1.z; ha[7]=(_Float16)a1.w;
            hb[0]=(_Float16)b0.x; hb[1]=(_Float16)b0.y; hb[2]=(_Float16)b0.z; hb[3]=(_Float16)b0.w;
            hb[4]=(_Float16)b1.x; hb[5]=(_Float16)b1.y; hb[6]=(_Float16)b1.z; hb[7]=(_Float16)b1.w;
            *(f16x8*)(As + r * LSTR + c8 * 8) = ha;
            *(f16x8*)(Bs + r * LSTR + c8 * 8) = hb;
        }
    }
    __syncthreads();

    const int lane = tid & 63;
    const int wid  = __builtin_amdgcn_readfirstlane(tid >> 6);
    const int l15  = lane & 15;
    const int quad = lane >> 4;

    f32x4 acc[2][8];
#pragma unroll
    for (int r = 0; r < 2; ++r)
#pragma unroll
        for (int c = 0; c < 8; ++c) acc[r][c] = (f32x4){0.f, 0.f, 0.f, 0.f};

#pragma unroll
    for (int ks = 0; ks < 4; ++ks) {
        f16x8 cfrag[8], rfrag[2];
#pragma unroll
        for (int c = 0; c < 8; ++c)
            cfrag[c] = *(const f16x8*)(Bs + (c * 16 + l15) * LSTR + ks * 32 + quad * 8);
#pragma unroll
        for (int r = 0; r < 2; ++r)
            rfrag[r] = *(const f16x8*)(As + (wid * 32 + r * 16 + l15) * LSTR + ks * 32 + quad * 8);
#pragma unroll
        for (int r = 0; r < 2; ++r)
#pragma unroll
            for (int c = 0; c < 8; ++c)
                acc[r][c] = __builtin_amdgcn_mfma_f32_16x16x32_f16(cfrag[c], rfrag[r], acc[r][c], 0, 0, 0);
    }

#pragma unroll
    for (int r = 0; r < 2; ++r) {
        const size_t row = rowbase + wid * 32 + r * 16 + l15;
#pragma unroll
        for (int c = 0; c < 8; ++c) {
            const int col = colbase + c * 16 + quad * 4;
            const float4 bv = *(const float4*)(bias + col);
            const f32x4 a = acc[r][c];
            f16x4 h;
            h[0] = (_Float16)(a[0] + bv.x); h[1] = (_Float16)(a[1] + bv.y);
            h[2] = (_Float16)(a[2] + bv.z); h[3] = (_Float16)(a[3] + bv.w);
            *(f16x4*)(Cout + row * 384 + col) = h;
        }
    }
}

// ---------------- out-proj GEMM: out_f32[M x 128] = ctx_h[M x 128] @ wout^T + bout ----------------
__global__ __launch_bounds__(256, 2) void gemm_out_kernel(
    const _Float16* __restrict__ Ain,   // f16 [M][128]
    const float*    __restrict__ Bin,   // f32 [128][128]
    const float*    __restrict__ bias,  // f32 [128]
    float*          __restrict__ Cout)  // f32 [M][128]
{
    __shared__ __align__(16) _Float16 As[128 * LSTR];
    __shared__ __align__(16) _Float16 Bs[128 * LSTR];
    const int tid = threadIdx.x;
    const int rowbase = blockIdx.y * 128;

    {
        const _Float16* A = Ain + (size_t)rowbase * EDIM;
#pragma unroll
        for (int it = 0; it < 8; ++it) {
            const int u = it * 256 + tid;
            const int r = u >> 4, c8 = u & 15;
            *(f16x8*)(As + r * LSTR + c8 * 8) = *(const f16x8*)(A + r * EDIM + c8 * 8);
            const float4 b0 = *(const float4*)(Bin + r * EDIM + c8 * 8);
            const float4 b1 = *(const float4*)(Bin + r * EDIM + c8 * 8 + 4);
            f16x8 hb;
            hb[0]=(_Float16)b0.x; hb[1]=(_Float16)b0.y; hb[2]=(_Float16)b0.z; hb[3]=(_Float16)b0.w;
            hb[4]=(_Float16)b1.x; hb[5]=(_Float16)b1.y; hb[6]=(_Float16)b1.z; hb[7]=(_Float16)b1.w;
            *(f16x8*)(Bs + r * LSTR + c8 * 8) = hb;
        }
    }
    __syncthreads();

    const int lane = tid & 63;
    const int wid  = __builtin_amdgcn_readfirstlane(tid >> 6);
    const int l15  = lane & 15;
    const int quad = lane >> 4;

    f32x4 acc[2][8];
#pragma unroll
    for (int r = 0; r < 2; ++r)
#pragma unroll
        for (int c = 0; c < 8; ++c) acc[r][c] = (f32x4){0.f, 0.f, 0.f, 0.f};

#pragma unroll
    for (int ks = 0; ks < 4; ++ks) {
        f16x8 cfrag[8], rfrag[2];
#pragma unroll
        for (int c = 0; c < 8; ++c)
            cfrag[c] = *(const f16x8*)(Bs + (c * 16 + l15) * LSTR + ks * 32 + quad * 8);
#pragma unroll
        for (int r = 0; r < 2; ++r)
            rfrag[r] = *(const f16x8*)(As + (wid * 32 + r * 16 + l15) * LSTR + ks * 32 + quad * 8);
#pragma unroll
        for (int r = 0; r < 2; ++r)
#pragma unroll
            for (int c = 0; c < 8; ++c)
                acc[r][c] = __builtin_amdgcn_mfma_f32_16x16x32_f16(cfrag[c], rfrag[r], acc[r][c], 0, 0, 0);
    }

#pragma unroll
    for (int r = 0; r < 2; ++r) {
        const size_t row = rowbase + wid * 32 + r * 16 + l15;
#pragma unroll
        for (int c = 0; c < 8; ++c) {
            const int col = c * 16 + quad * 4;
            const float4 bv = *(const float4*)(bias + col);
            const f32x4 a = acc[r][c];
            *(float4*)(Cout + row * 128 + col) =
                make_float4(a[0] + bv.x, a[1] + bv.y, a[2] + bv.z, a[3] + bv.w);
        }
    }
}

// ---------------- per-sample flash attention over fp16 QKV ----------------
__global__ __launch_bounds__(256, 2) void attn2h_kernel(
    const _Float16* __restrict__ qkv,   // [TOTAL][384] fp16
    const int*      __restrict__ ag,
    const int*      __restrict__ offs,
    _Float16*       __restrict__ ctx)   // [TOTAL][128] fp16
{
    __shared__ __align__(16) float kvs[8][AMAX * KVSTR];
    const int b    = blockIdx.x;
    const int n    = ag[b];
    const int off  = offs[b];
    const int tid  = threadIdx.x;
    const int lane = tid & 63;
    const int wid  = __builtin_amdgcn_readfirstlane(tid >> 6);
    float* kw = kvs[wid * 2 + 0];
    float* vw = kvs[wid * 2 + 1];
    const bool valid = lane < n;
    const _Float16* rowp = qkv + (size_t)(off + lane) * 384;

#pragma unroll
    for (int m = 0; m < 2; ++m) {
        const int h = wid * 2 + m;
        float qa[DHEAD], ka[DHEAD], va[DHEAD];
        if (valid) {
            const f16x8 q0 = *(const f16x8*)(rowp + h * 16);
            const f16x8 q1 = *(const f16x8*)(rowp + h * 16 + 8);
            const f16x8 k0 = *(const f16x8*)(rowp + 128 + h * 16);
            const f16x8 k1 = *(const f16x8*)(rowp + 128 + h * 16 + 8);
            const f16x8 v0 = *(const f16x8*)(rowp + 256 + h * 16);
            const f16x8 v1 = *(const f16x8*)(rowp + 256 + h * 16 + 8);
#pragma unroll
            for (int d = 0; d < 8; ++d) {
                qa[d] = (float)q0[d]; qa[d + 8] = (float)q1[d];
                ka[d] = (float)k0[d]; ka[d + 8] = (float)k1[d];
                va[d] = (float)v0[d]; va[d + 8] = (float)v1[d];
            }
        } else {
#pragma unroll
            for (int d = 0; d < DHEAD; ++d) { qa[d] = 0.f; ka[d] = 0.f; va[d] = 0.f; }
        }
#pragma unroll
        for (int d = 0; d < DHEAD; ++d) qa[d] *= 0.25f;   // 1/sqrt(16)
#pragma unroll
        for (int d4 = 0; d4 < 4; ++d4) {
            *(float4*)(kw + lane * KVSTR + d4 * 4) = make_float4(ka[d4*4], ka[d4*4+1], ka[d4*4+2], ka[d4*4+3]);
            *(float4*)(vw + lane * KVSTR + d4 * 4) = make_float4(va[d4*4], va[d4*4+1], va[d4*4+2], va[d4*4+3]);
        }

        float mrun = -1e30f, lrun = 0.f;
        float cacc[DHEAD];
#pragma unroll
        for (int d = 0; d < DHEAD; ++d) cacc[d] = 0.f;
        const int nch = (n + 15) >> 4;
        for (int ch = 0; ch < nch; ++ch) {
            const int jb = ch << 4;
            float s[16], p[16];
#pragma unroll
            for (int jj = 0; jj < 16; ++jj) {
                const float4* kr = (const float4*)(kw + (jb + jj) * KVSTR);
                const float4 k0 = kr[0], k1 = kr[1], k2 = kr[2], k3 = kr[3];
                const float kk[16] = {k0.x,k0.y,k0.z,k0.w, k1.x,k1.y,k1.z,k1.w,
                                      k2.x,k2.y,k2.z,k2.w, k3.x,k3.y,k3.z,k3.w};
                float a = 0.f;
#pragma unroll
                for (int d = 0; d < DHEAD; ++d) a = fmaf(qa[d], kk[d], a);
                s[jj] = (jb + jj < n) ? a : -1e30f;
            }
            float mc = s[0];
#pragma unroll
            for (int jj = 1; jj < 16; ++jj) mc = fmaxf(mc, s[jj]);
            const float mnew  = fmaxf(mrun, mc);
            const float alpha = __expf(mrun - mnew);
            float psum = 0.f;
#pragma unroll
            for (int jj = 0; jj < 16; ++jj) { p[jj] = __expf(s[jj] - mnew); psum += p[jj]; }
            lrun = fmaf(lrun, alpha, psum);
#pragma unroll
            for (int d = 0; d < DHEAD; ++d) cacc[d] *= alpha;
#pragma unroll
            for (int jj = 0; jj < 16; ++jj) {
                const float4* vr = (const float4*)(vw + (jb + jj) * KVSTR);
                const float4 v0 = vr[0], v1 = vr[1], v2 = vr[2], v3 = vr[3];
                const float vv[16] = {v0.x,v0.y,v0.z,v0.w, v1.x,v1.y,v1.z,v1.w,
                                      v2.x,v2.y,v2.z,v2.w, v3.x,v3.y,v3.z,v3.w};
                const float pj = p[jj];
#pragma unroll
                for (int d = 0; d < DHEAD; ++d) cacc[d] = fmaf(pj, vv[d], cacc[d]);
            }
            mrun = mnew;
        }
        if (valid) {
            const float inv = 1.0f / lrun;
            f16x8 o0, o1;
#pragma unroll
            for (int d = 0; d < 8; ++d) {
                o0[d] = (_Float16)(cacc[d] * inv);
                o1[d] = (_Float16)(cacc[d + 8] * inv);
            }
            _Float16* crow = ctx + (size_t)(off + lane) * 128 + h * 16;
            *(f16x8*)(crow)     = o0;
            *(f16x8*)(crow + 8) = o1;
        }
    }
}

// ================= fallback: fused fp32 kernel (used if ws too small) =================
__global__ __launch_bounds__(256, 2) void attn_fused_kernel(
    const float* __restrict__ x, const float* __restrict__ win,
    const float* __restrict__ bin, const float* __restrict__ wout,
    const float* __restrict__ bout, const int* __restrict__ ag,
    const int* __restrict__ offs, float* __restrict__ out)
{
    __shared__ __align__(16) float xs[AMAX * XSTR];
    __shared__ __align__(16) float kvs[8][AMAX * KVSTR];
    const int b = blockIdx.x, n = ag[b], off = offs[b];
    const int tid = threadIdx.x, lane = tid & 63;
    const int wid = __builtin_amdgcn_readfirstlane(tid >> 6);
#pragma unroll
    for (int it = 0; it < 8; ++it) {
        const int f4 = it * 256 + tid;
        const int r = f4 >> 5, c = (f4 & 31) << 2;
        float4 v = make_float4(0.f, 0.f, 0.f, 0.f);
        if (r < n) v = *(const float4*)(x + (size_t)(off + r) * EDIM + c);
        float* d = xs + r * XSTR + c;
        d[0]=v.x; d[1]=v.y; d[2]=v.z; d[3]=v.w;
    }
    __syncthreads();
    float* kw = kvs[wid*2+0]; float* vw = kvs[wid*2+1];
    const float* xrow = xs + lane * XSTR;
    float ctxk[2][DHEAD];
#pragma unroll
    for (int m = 0; m < 2; ++m) {
        const int h = wid * 2 + m;
        float qa[DHEAD], ka[DHEAD], va[DHEAD];
#pragma unroll
        for (int d = 0; d < DHEAD; ++d) { qa[d]=0.f; ka[d]=0.f; va[d]=0.f; }
        const float* wq = win + (size_t)(h*DHEAD)*EDIM;
        const float* wk = win + (size_t)(EDIM + h*DHEAD)*EDIM;
        const float* wv = win + (size_t)(2*EDIM + h*DHEAD)*EDIM;
        for (int k = 0; k < EDIM; ++k) {
            const float xv = xrow[k];
#pragma unroll
            for (int d = 0; d < DHEAD; ++d) {
                qa[d] = fmaf(xv, wq[d*EDIM+k], qa[d]);
                ka[d] = fmaf(xv, wk[d*EDIM+k], ka[d]);
                va[d] = fmaf(xv, wv[d*EDIM+k], va[d]);
            }
        }
#pragma unroll
        for (int d = 0; d < DHEAD; ++d) {
            qa[d] = (qa[d] + bin[h*DHEAD+d]) * 0.25f;
            ka[d] += bin[EDIM + h*DHEAD + d];
            va[d] += bin[2*EDIM + h*DHEAD + d];
        }
#pragma unroll
        for (int d = 0; d < DHEAD; ++d) { kw[lane*KVSTR+d] = ka[d]; vw[lane*KVSTR+d] = va[d]; }
        float mrun = -1e30f, lrun = 0.f, cacc[DHEAD];
#pragma unroll
        for (int d = 0; d < DHEAD; ++d) cacc[d] = 0.f;
        const int nch = (n + 15) >> 4;
        for (int ch = 0; ch < nch; ++ch) {
            const int jb = ch << 4;
            float s[16], p[16];
#pragma unroll
            for (int jj = 0; jj < 16; ++jj) {
                const float4* kr = (const float4*)(kw + (jb + jj) * KVSTR);
                const float4 k0=kr[0],k1=kr[1],k2=kr[2],k3=kr[3];
                const float kk[16] = {k0.x,k0.y,k0.z,k0.w,k1.x,k1.y,k1.z,k1.w,
                                      k2.x,k2.y,k2.z,k2.w,k3.x,k3.y,k3.z,k3.w};
                float a = 0.f;
#pragma unroll
                for (int d = 0; d < DHEAD; ++d) a = fmaf(qa[d], kk[d], a);
                s[jj] = (jb + jj < n) ? a : -1e30f;
            }
            float mc = s[0];
#pragma unroll
            for (int jj = 1; jj < 16; ++jj) mc = fmaxf(mc, s[jj]);
            const float mnew = fmaxf(mrun, mc);
            const float alpha = __expf(mrun - mnew);
            float psum = 0.f;
#pragma unroll
            for (int jj = 0; jj < 16; ++jj) { p[jj] = __expf(s[jj]-mnew); psum += p[jj]; }
            lrun = fmaf(lrun, alpha, psum);
#pragma unroll
            for (int d = 0; d < DHEAD; ++d) cacc[d] *= alpha;
#pragma unroll
            for (int jj = 0; jj < 16; ++jj) {
                const float4* vr = (const float4*)(vw + (jb + jj) * KVSTR);
                const float4 v0=vr[0],v1=vr[1],v2=vr[2],v3=vr[3];
                const float vv[16] = {v0.x,v0.y,v0.z,v0.w,v1.x,v1.y,v1.z,v1.w,
                                      v2.x,v2.y,v2.z,v2.w,v3.x,v3.y,v3.z,v3.w};
                const float pj = p[jj];
#pragma unroll
                for (int d = 0; d < DHEAD; ++d) cacc[d] = fmaf(pj, vv[d], cacc[d]);
            }
            mrun = mnew;
        }
        const float inv = 1.0f / lrun;
#pragma unroll
        for (int d = 0; d < DHEAD; ++d) ctxk[m][d] = cacc[d] * inv;
    }
    __syncthreads();
#pragma unroll
    for (int m = 0; m < 2; ++m) {
        const int h = wid * 2 + m;
#pragma unroll
        for (int d = 0; d < DHEAD; ++d) xs[lane*XSTR + h*DHEAD + d] = ctxk[m][d];
    }
    __syncthreads();
    const int c0 = wid * 32;
#pragma unroll
    for (int ct = 0; ct < 4; ++ct) {
        const int cc = c0 + ct * 8;
        float a8[8];
#pragma unroll
        for (int j = 0; j < 8; ++j) a8[j] = 0.f;
#pragma unroll 4
        for (int e = 0; e < EDIM; ++e) {
            const float cv = xrow[e];
#pragma unroll
            for (int j = 0; j < 8; ++j) a8[j] = fmaf(cv, wout[(size_t)(cc+j)*EDIM+e], a8[j]);
        }
        if (lane < n) {
            float* orow = out + (size_t)(off + lane) * EDIM + cc;
#pragma unroll
            for (int j = 0; j < 8; ++j) orow[j] = a8[j] + bout[cc+j];
        }
    }
}

extern "C" void kernel_launch(void* const* d_in, const int* in_sizes, int n_in,
                              void* d_out, int out_size, void* d_ws, size_t ws_size,
                              hipStream_t stream) {
    const float* x   = (const float*)d_in[0];
    const float* win = (const float*)d_in[1];
    const float* bin = (const float*)d_in[2];
    const float* wo  = (const float*)d_in[3];
    const float* bo  = (const float*)d_in[4];
    const int*   ag  = (const int*)d_in[5];
    float* out = (float*)d_out;

    const size_t need = (size_t)TOTAL * 512 * sizeof(_Float16) + NB * sizeof(int);
    if (ws_size >= need) {
        _Float16* qkvh = (_Float16*)d_ws;                       // [TOTAL][384]
        _Float16* ctxh = qkvh + (size_t)TOTAL * 384;            // [TOTAL][128]
        int* offs = (int*)(qkvh + (size_t)TOTAL * 512);
        scan_kernel<<<1, 256, 0, stream>>>(ag, offs);
        gemm_qkv_kernel<<<dim3(3, TOTAL / 128), 256, 0, stream>>>(x, win, bin, qkvh);
        attn2h_kernel<<<NB, 256, 0, stream>>>(qkvh, ag, offs, ctxh);
        gemm_out_kernel<<<dim3(1, TOTAL / 128), 256, 0, stream>>>(ctxh, wo, bo, out);
    } else {
        int* offs = (int*)d_ws;
        scan_kernel<<<1, 256, 0, stream>>>(ag, offs);
        attn_fused_kernel<<<NB, 256, 0, stream>>>(x, win, bin, wo, bo, ag, offs, out);
    }
}